// Round 1
// baseline (278.841 us; speedup 1.0000x reference)
//
#include <hip/hip_runtime.h>
#include <math.h>

// Problem constants
#define BHN     55392          // B*H*N = 8*12*577 (token count)
#define NTOK    577
#define HD      64
#define EPS_F   1e-6f
#define TOTAL_ELEMS 31961184   // BHN * 577
#define TOTAL_VEC   7990296    // TOTAL_ELEMS / 4

typedef float f32x4 __attribute__((ext_vector_type(4)));

// ---------------------------------------------------------------------------
// Kernel A v3: per-token sigma MLP -> folded quadratic-form coefficients.
// coef[tok] = { a, b, c, pack }, w = a*dx^2 + b*dx*dy + c*dy^2.
// v3: W1 read via UNIFORM loads (compiler scalarizes to s_load + v_fmac with
// SGPR operand) instead of LDS broadcast — removes the 1024 ds_read_b128/wave
// that made v2 LDS-issue-bound (~6-20us of LDS pipe vs ~3.7us of FMA).
// No LDS, no __syncthreads. Divergent early-return replaced by clamp so
// control flow stays uniform (prerequisite for scalarization); tail threads
// redundantly recompute token BHN-1 (same-value write, benign).
// ---------------------------------------------------------------------------
__global__ __launch_bounds__(256) void sigma_coef_kernel(
    const float* __restrict__ q,  const float* __restrict__ W1,
    const float* __restrict__ b1, const float* __restrict__ W2,
    const float* __restrict__ b2, float4* __restrict__ coef)
{
    int tok = blockIdx.x * 256 + threadIdx.x;
    if (tok >= BHN) tok = BHN - 1;                   // clamp: uniform CF

    float h[HD];
    #pragma unroll
    for (int t = 0; t < HD; ++t) h[t] = 0.0f;

    // h = q @ W1  (b1 added in epilogue). Rolled kk-loop: body = 1 vload
    // (per-thread q chunk, prefetched) + 256 uniform W1 reads (s_load) +
    // 256 v_fmac. Scalar loads hit sL1 (W1 = 16 KB, resident).
    const float4* q4 = (const float4*)(q + (size_t)tok * HD);
    float4 qv = q4[0];
    #pragma unroll 1
    for (int kk = 0; kk < 16; ++kk) {
        const int kn = (kk < 15) ? (kk + 1) : 15;
        float4 qnext = q4[kn];                       // prefetch next chunk
        const float* __restrict__ wr = W1 + kk * 4 * HD;
        float qk[4] = {qv.x, qv.y, qv.z, qv.w};
        #pragma unroll
        for (int d = 0; d < 4; ++d) {
            float qs = qk[d];
            #pragma unroll
            for (int t = 0; t < HD; ++t)
                h[t] = fmaf(qs, wr[d * HD + t], h[t]);
        }
        qv = qnext;
    }

    // s = gelu(h + b1) @ W2 + b2.  erf via A&S 7.1.26 (|err| <= 1.5e-7),
    // branchless (~20 instrs/term vs libm erff's branchy ~60).
    float s0 = b2[0], s1 = b2[1], s2 = b2[2];
    #pragma unroll
    for (int t = 0; t < HD; ++t) {
        float x = h[t] + b1[t];
        float z = x * 0.70710678118654752f;
        float az = fabsf(z);
        float k = __builtin_amdgcn_rcpf(fmaf(0.3275911f, az, 1.0f));
        float poly = k * (0.254829592f + k * (-0.284496736f +
                     k * (1.421413741f + k * (-1.453152027f +
                     k * 1.061405429f))));
        float om = poly * __expf(-z * z);            // 1 - erf(|z|)
        float erfz = copysignf(1.0f - om, z);
        float g = 0.5f * x * (1.0f + erfz);
        s0 = fmaf(g, W2[t*3 + 0], s0);
        s1 = fmaf(g, W2[t*3 + 1], s1);
        s2 = fmaf(g, W2[t*3 + 2], s2);
    }

    float sx = fmaxf(s0, 0.0f) + 1.0f;
    float sy = fmaxf(s1, 0.0f) + 1.0f;
    // tanh(x) = (e^2x - 1)/(e^2x + 1), branchless; s2 is O(0.02) so no overflow
    float ex = __expf(2.0f * s2);
    float rho = 0.99f * ((ex - 1.0f) * __builtin_amdgcn_rcpf(ex + 1.0f));
    float sxx = sx * sx, syy = sy * sy;
    float sxy = rho * sx * sy;
    float det = sxx * syy - sxy * sxy;               // >= 0.0199
    float inv_det = 1.0f / det;

    float a = -0.5f * syy * inv_det;
    float b =  sxy * inv_det;
    float c = -0.5f * sxx * inv_det;

    int i = tok % NTOK;
    float pack;
    if (i == 0) { a = 0.0f; b = 0.0f; c = 0.0f; pack = 0.0f; }
    else {
        int ip = i - 1;
        int ri = ip / 24;
        int ci = ip - ri * 24;
        pack = (float)(ri * 32 + ci);
    }
    coef[tok] = make_float4(a, b, c, pack);          // clamped dup write: same value
}

// ---------------------------------------------------------------------------
// Kernel B v3: elementwise mask. rowmax(kernel)==1 structurally, so
// probs = clip(exp(w), eps, 1-eps). Numerics IDENTICAL to the passing v2
// (absmax-sensitive 10x-amplified logit chain untouched). v3 adds
// non-temporal load/store on the two 128 MB streaming buffers (read-once /
// write-once — no reuse, keep them out of L2/LLC residency).
// ---------------------------------------------------------------------------
__global__ __launch_bounds__(256) void mask_kernel(
    const f32x4* __restrict__ u4, const float4* __restrict__ coef,
    f32x4* __restrict__ out4)
{
    int vid = blockIdx.x * 256 + threadIdx.x;
    if (vid >= TOTAL_VEC) return;

    int e0 = vid * 4;
    unsigned row0 = (unsigned)e0 / 577u;             // magic-div
    int j0 = e0 - (int)row0 * 577;

    // at most one row crossing within 4 elems; row0+1 stays < BHN (last vec
    // has j0 = 573 -> no crossing), so the load below is always in-bounds.
    unsigned row1 = row0 + ((j0 + 3 >= 577) ? 1u : 0u);
    float4 cf0 = coef[row0];
    float4 cf1 = coef[row1];
    f32x4 uu = __builtin_nontemporal_load(&u4[vid]);

    float um[4] = {uu[0], uu[1], uu[2], uu[3]};
    float res[4];

    #pragma unroll
    for (int m = 0; m < 4; ++m) {
        int j = j0 + m;
        bool crossed = (j >= 577);
        if (crossed) j -= 577;
        float4 cf;
        cf.x = crossed ? cf1.x : cf0.x;
        cf.y = crossed ? cf1.y : cf0.y;
        cf.z = crossed ? cf1.z : cf0.z;
        cf.w = crossed ? cf1.w : cf0.w;
        int rc = (int)cf.w;

        float dx = 0.0f, dy = 0.0f;
        if (j > 0) {
            unsigned jj = (unsigned)(j - 1);
            unsigned rj = jj / 24u;                  // magic-div
            unsigned cj = jj - rj * 24u;
            dx = (float)((rc >> 5) - (int)rj);
            dy = (float)((rc & 31) - (int)cj);
        }

        // w = a*dx^2 + b*dx*dy + c*dy^2  (<= 0)
        float w = fmaf(fmaf(cf.x, dx, cf.y * dy), dx, cf.z * (dy * dy));

        float p = __expf(w);
        p = fminf(fmaxf(p, EPS_F), 1.0f - EPS_F);

        float uk  = um[m];
        float num = p * uk;                          // >= 1e-12
        float den = (1.0f - p) * (1.0f - uk);
        float t = 10.0f * (__logf(num) - __logf(den));   // (logits+noise)/TEMP

        res[m] = __builtin_amdgcn_rcpf(1.0f + __expf(-t));
    }

    f32x4 r;
    r[0] = res[0]; r[1] = res[1]; r[2] = res[2]; r[3] = res[3];
    __builtin_nontemporal_store(r, &out4[vid]);
}

// ---------------------------------------------------------------------------
extern "C" void kernel_launch(void* const* d_in, const int* in_sizes, int n_in,
                              void* d_out, int out_size, void* d_ws, size_t ws_size,
                              hipStream_t stream) {
    const float* q  = (const float*)d_in[0];
    const float* W1 = (const float*)d_in[1];
    const float* b1 = (const float*)d_in[2];
    const float* W2 = (const float*)d_in[3];
    const float* b2 = (const float*)d_in[4];
    const float* u  = (const float*)d_in[5];
    // d_in[6] = dists: recomputed on the fly, not loaded.

    float4* coef = (float4*)d_ws;                    // 886 KB scratch

    sigma_coef_kernel<<<(BHN + 255) / 256, 256, 0, stream>>>(q, W1, b1, W2, b2, coef);
    mask_kernel<<<(TOTAL_VEC + 255) / 256, 256, 0, stream>>>(
        (const f32x4*)u, coef, (f32x4*)d_out);
}

// Round 2
// 257.674 us; speedup vs baseline: 1.0821x; 1.0821x over previous
//
#include <hip/hip_runtime.h>
#include <math.h>

// Problem constants
#define BHN     55392          // B*H*N = 8*12*577 (token count)
#define NTOK    577
#define HD      64
#define EPS_F   1e-6f
#define TOTAL_ELEMS 31961184   // BHN * 577
#define TOTAL_VEC   7990296    // TOTAL_ELEMS / 4

typedef float f32x4 __attribute__((ext_vector_type(4)));

// ---------------------------------------------------------------------------
// Kernel A v4: per-token sigma MLP -> folded quadratic-form coefficients.
// coef[tok] = { a, b, c, pack }, w = a*dx^2 + b*dx*dy + c*dy^2.
// v4: back to LDS-broadcast W1 (v3's uniform-global-load scalarization did
// not materialize -> 1024 per-lane VMEM loads/wave, +22us). NEW: 4 threads
// per token (sub = tid&3 owns 16 h-columns) -> 866 blocks instead of 216,
// occupancy 0.84 -> 3.4 waves/SIMD so LDS-issue and VALU overlap across
// waves instead of serializing at <1 wave/SIMD. Cross-thread cost: 9
// __shfl_xor + one lane-divergent 16B store per token.
// ---------------------------------------------------------------------------
__global__ __launch_bounds__(256) void sigma_coef_kernel(
    const float* __restrict__ q,  const float* __restrict__ W1,
    const float* __restrict__ b1, const float* __restrict__ W2,
    const float* __restrict__ b2, float4* __restrict__ coef)
{
    __shared__ float w1s[64 * 64];           // 16 KB
    const int tid = threadIdx.x;

    // cooperative W1 stage: 1024 float4 / 256 threads = 4 each, coalesced
    {
        const float4* w4 = (const float4*)W1;
        float4* s4 = (float4*)w1s;
        #pragma unroll
        for (int i = 0; i < 4; ++i)
            s4[tid + 256 * i] = w4[tid + 256 * i];
    }
    __syncthreads();

    int tok = (blockIdx.x * 256 + tid) >> 2;
    const int sub = tid & 3;                 // 4 consecutive lanes per token
    if (tok >= BHN) tok = BHN - 1;           // tail dup-compute, same-value write

    const int t0 = sub * 16;                 // this thread's h-column range

    float h[16];
    #pragma unroll
    for (int t = 0; t < 16; ++t) h[t] = 0.0f;

    // h[t0..t0+15] = q @ W1[:, t0..t0+15].  Rolled kk-loop: body = 1 vload
    // (16-row broadcast-coalesced) + 16 broadcast ds_read_b128 + 64 v_fmac.
    // Sub-group bank aliasing is 2-way (sub0/sub2, sub1/sub3) = free (m136).
    const float4* q4 = (const float4*)(q + (size_t)tok * HD);
    float4 qv = q4[0];
    #pragma unroll 1
    for (int kk = 0; kk < 16; ++kk) {
        const int kn = (kk < 15) ? (kk + 1) : 15;
        float4 qnext = q4[kn];                       // prefetch next chunk
        float qk[4] = {qv.x, qv.y, qv.z, qv.w};
        #pragma unroll
        for (int d = 0; d < 4; ++d) {
            const float4* wrow = (const float4*)(w1s + (kk * 4 + d) * HD + t0);
            float qs = qk[d];
            #pragma unroll
            for (int t4 = 0; t4 < 4; ++t4) {
                float4 wv = wrow[t4];
                h[4*t4+0] = fmaf(qs, wv.x, h[4*t4+0]);
                h[4*t4+1] = fmaf(qs, wv.y, h[4*t4+1]);
                h[4*t4+2] = fmaf(qs, wv.z, h[4*t4+2]);
                h[4*t4+3] = fmaf(qs, wv.w, h[4*t4+3]);
            }
        }
        qv = qnext;
    }

    // partial s = gelu(h + b1) @ W2 over this thread's 16 columns.
    // erf via A&S 7.1.26 (|err| <= 1.5e-7), branchless.
    float s0 = 0.0f, s1 = 0.0f, s2 = 0.0f;
    #pragma unroll
    for (int t = 0; t < 16; ++t) {
        float x = h[t] + b1[t0 + t];
        float z = x * 0.70710678118654752f;
        float az = fabsf(z);
        float k = __builtin_amdgcn_rcpf(fmaf(0.3275911f, az, 1.0f));
        float poly = k * (0.254829592f + k * (-0.284496736f +
                     k * (1.421413741f + k * (-1.453152027f +
                     k * 1.061405429f))));
        float om = poly * __expf(-z * z);            // 1 - erf(|z|)
        float erfz = copysignf(1.0f - om, z);
        float g = 0.5f * x * (1.0f + erfz);
        s0 = fmaf(g, W2[(t0 + t)*3 + 0], s0);
        s1 = fmaf(g, W2[(t0 + t)*3 + 1], s1);
        s2 = fmaf(g, W2[(t0 + t)*3 + 2], s2);
    }

    // 4-lane reduction within the token's sub-group (lanes are adjacent)
    s0 += __shfl_xor(s0, 1); s0 += __shfl_xor(s0, 2);
    s1 += __shfl_xor(s1, 1); s1 += __shfl_xor(s1, 2);
    s2 += __shfl_xor(s2, 1); s2 += __shfl_xor(s2, 2);
    s0 += b2[0]; s1 += b2[1]; s2 += b2[2];

    float sx = fmaxf(s0, 0.0f) + 1.0f;
    float sy = fmaxf(s1, 0.0f) + 1.0f;
    // tanh(x) = (e^2x - 1)/(e^2x + 1), branchless; s2 is O(0.02) so no overflow
    float ex = __expf(2.0f * s2);
    float rho = 0.99f * ((ex - 1.0f) * __builtin_amdgcn_rcpf(ex + 1.0f));
    float sxx = sx * sx, syy = sy * sy;
    float sxy = rho * sx * sy;
    float det = sxx * syy - sxy * sxy;               // >= 0.0199
    float inv_det = 1.0f / det;

    float a = -0.5f * syy * inv_det;
    float b =  sxy * inv_det;
    float c = -0.5f * sxx * inv_det;

    int i = tok % NTOK;
    float pack;
    if (i == 0) { a = 0.0f; b = 0.0f; c = 0.0f; pack = 0.0f; }
    else {
        int ip = i - 1;
        int ri = ip / 24;
        int ci = ip - ri * 24;
        pack = (float)(ri * 32 + ci);
    }
    if (sub == 0)
        coef[tok] = make_float4(a, b, c, pack);      // dup groups rewrite same value
}

// ---------------------------------------------------------------------------
// Kernel B v3 (unchanged): elementwise mask. rowmax(kernel)==1 structurally,
// so probs = clip(exp(w), eps, 1-eps). Numerics identical to the passing v2.
// nt load/store on the two 128 MB streaming buffers keeps them from
// thrashing L2 (coef re-reads stay hot).
// ---------------------------------------------------------------------------
__global__ __launch_bounds__(256) void mask_kernel(
    const f32x4* __restrict__ u4, const float4* __restrict__ coef,
    f32x4* __restrict__ out4)
{
    int vid = blockIdx.x * 256 + threadIdx.x;
    if (vid >= TOTAL_VEC) return;

    int e0 = vid * 4;
    unsigned row0 = (unsigned)e0 / 577u;             // magic-div
    int j0 = e0 - (int)row0 * 577;

    // at most one row crossing within 4 elems; row0+1 stays < BHN (last vec
    // has j0 = 573 -> no crossing), so the load below is always in-bounds.
    unsigned row1 = row0 + ((j0 + 3 >= 577) ? 1u : 0u);
    float4 cf0 = coef[row0];
    float4 cf1 = coef[row1];
    f32x4 uu = __builtin_nontemporal_load(&u4[vid]);

    float um[4] = {uu[0], uu[1], uu[2], uu[3]};
    float res[4];

    #pragma unroll
    for (int m = 0; m < 4; ++m) {
        int j = j0 + m;
        bool crossed = (j >= 577);
        if (crossed) j -= 577;
        float4 cf;
        cf.x = crossed ? cf1.x : cf0.x;
        cf.y = crossed ? cf1.y : cf0.y;
        cf.z = crossed ? cf1.z : cf0.z;
        cf.w = crossed ? cf1.w : cf0.w;
        int rc = (int)cf.w;

        float dx = 0.0f, dy = 0.0f;
        if (j > 0) {
            unsigned jj = (unsigned)(j - 1);
            unsigned rj = jj / 24u;                  // magic-div
            unsigned cj = jj - rj * 24u;
            dx = (float)((rc >> 5) - (int)rj);
            dy = (float)((rc & 31) - (int)cj);
        }

        // w = a*dx^2 + b*dx*dy + c*dy^2  (<= 0)
        float w = fmaf(fmaf(cf.x, dx, cf.y * dy), dx, cf.z * (dy * dy));

        float p = __expf(w);
        p = fminf(fmaxf(p, EPS_F), 1.0f - EPS_F);

        float uk  = um[m];
        float num = p * uk;                          // >= 1e-12
        float den = (1.0f - p) * (1.0f - uk);
        float t = 10.0f * (__logf(num) - __logf(den));   // (logits+noise)/TEMP

        res[m] = __builtin_amdgcn_rcpf(1.0f + __expf(-t));
    }

    f32x4 r;
    r[0] = res[0]; r[1] = res[1]; r[2] = res[2]; r[3] = res[3];
    __builtin_nontemporal_store(r, &out4[vid]);
}

// ---------------------------------------------------------------------------
extern "C" void kernel_launch(void* const* d_in, const int* in_sizes, int n_in,
                              void* d_out, int out_size, void* d_ws, size_t ws_size,
                              hipStream_t stream) {
    const float* q  = (const float*)d_in[0];
    const float* W1 = (const float*)d_in[1];
    const float* b1 = (const float*)d_in[2];
    const float* W2 = (const float*)d_in[3];
    const float* b2 = (const float*)d_in[4];
    const float* u  = (const float*)d_in[5];
    // d_in[6] = dists: recomputed on the fly, not loaded.

    float4* coef = (float4*)d_ws;                    // 886 KB scratch

    sigma_coef_kernel<<<(BHN * 4 + 255) / 256, 256, 0, stream>>>(q, W1, b1, W2, b2, coef);
    mask_kernel<<<(TOTAL_VEC + 255) / 256, 256, 0, stream>>>(
        (const f32x4*)u, coef, (f32x4*)d_out);
}

// Round 3
// 256.479 us; speedup vs baseline: 1.0872x; 1.0047x over previous
//
#include <hip/hip_runtime.h>
#include <math.h>

// Problem constants
#define BHN     55392          // B*H*N = 8*12*577 (token count)
#define NTOK    577
#define HD      64
#define EPS_F   1e-6f
#define TOTAL_ELEMS 31961184   // BHN * 577
#define TOTAL_V8    3995148    // TOTAL_ELEMS / 8

typedef float f32x4 __attribute__((ext_vector_type(4)));

// ---------------------------------------------------------------------------
// Kernel A v4 (unchanged): per-token sigma MLP -> folded quadratic coeffs.
// coef[tok] = { a, b, c, pack }, w = a*dx^2 + b*dx*dy + c*dy^2.
// 4 threads/token (sub = tid&3 owns 16 h-columns) -> 866 blocks, 3.4
// waves/SIMD so LDS-broadcast issue overlaps across waves.
// ---------------------------------------------------------------------------
__global__ __launch_bounds__(256) void sigma_coef_kernel(
    const float* __restrict__ q,  const float* __restrict__ W1,
    const float* __restrict__ b1, const float* __restrict__ W2,
    const float* __restrict__ b2, float4* __restrict__ coef)
{
    __shared__ float w1s[64 * 64];           // 16 KB
    const int tid = threadIdx.x;

    // cooperative W1 stage: 1024 float4 / 256 threads = 4 each, coalesced
    {
        const float4* w4 = (const float4*)W1;
        float4* s4 = (float4*)w1s;
        #pragma unroll
        for (int i = 0; i < 4; ++i)
            s4[tid + 256 * i] = w4[tid + 256 * i];
    }
    __syncthreads();

    int tok = (blockIdx.x * 256 + tid) >> 2;
    const int sub = tid & 3;                 // 4 consecutive lanes per token
    if (tok >= BHN) tok = BHN - 1;           // tail dup-compute, same-value write

    const int t0 = sub * 16;                 // this thread's h-column range

    float h[16];
    #pragma unroll
    for (int t = 0; t < 16; ++t) h[t] = 0.0f;

    // h[t0..t0+15] = q @ W1[:, t0..t0+15].  Rolled kk-loop: body = 1 vload
    // + 16 broadcast ds_read_b128 + 64 v_fmac. Sub-group bank aliasing is
    // 2-way (free, m136).
    const float4* q4 = (const float4*)(q + (size_t)tok * HD);
    float4 qv = q4[0];
    #pragma unroll 1
    for (int kk = 0; kk < 16; ++kk) {
        const int kn = (kk < 15) ? (kk + 1) : 15;
        float4 qnext = q4[kn];                       // prefetch next chunk
        float qk[4] = {qv.x, qv.y, qv.z, qv.w};
        #pragma unroll
        for (int d = 0; d < 4; ++d) {
            const float4* wrow = (const float4*)(w1s + (kk * 4 + d) * HD + t0);
            float qs = qk[d];
            #pragma unroll
            for (int t4 = 0; t4 < 4; ++t4) {
                float4 wv = wrow[t4];
                h[4*t4+0] = fmaf(qs, wv.x, h[4*t4+0]);
                h[4*t4+1] = fmaf(qs, wv.y, h[4*t4+1]);
                h[4*t4+2] = fmaf(qs, wv.z, h[4*t4+2]);
                h[4*t4+3] = fmaf(qs, wv.w, h[4*t4+3]);
            }
        }
        qv = qnext;
    }

    // partial s = gelu(h + b1) @ W2 over this thread's 16 columns.
    // erf via A&S 7.1.26 (|err| <= 1.5e-7), branchless.
    float s0 = 0.0f, s1 = 0.0f, s2 = 0.0f;
    #pragma unroll
    for (int t = 0; t < 16; ++t) {
        float x = h[t] + b1[t0 + t];
        float z = x * 0.70710678118654752f;
        float az = fabsf(z);
        float k = __builtin_amdgcn_rcpf(fmaf(0.3275911f, az, 1.0f));
        float poly = k * (0.254829592f + k * (-0.284496736f +
                     k * (1.421413741f + k * (-1.453152027f +
                     k * 1.061405429f))));
        float om = poly * __expf(-z * z);            // 1 - erf(|z|)
        float erfz = copysignf(1.0f - om, z);
        float g = 0.5f * x * (1.0f + erfz);
        s0 = fmaf(g, W2[(t0 + t)*3 + 0], s0);
        s1 = fmaf(g, W2[(t0 + t)*3 + 1], s1);
        s2 = fmaf(g, W2[(t0 + t)*3 + 2], s2);
    }

    // 4-lane reduction within the token's sub-group (lanes are adjacent)
    s0 += __shfl_xor(s0, 1); s0 += __shfl_xor(s0, 2);
    s1 += __shfl_xor(s1, 1); s1 += __shfl_xor(s1, 2);
    s2 += __shfl_xor(s2, 1); s2 += __shfl_xor(s2, 2);
    s0 += b2[0]; s1 += b2[1]; s2 += b2[2];

    float sx = fmaxf(s0, 0.0f) + 1.0f;
    float sy = fmaxf(s1, 0.0f) + 1.0f;
    // tanh(x) = (e^2x - 1)/(e^2x + 1), branchless; s2 is O(0.02) so no overflow
    float ex = __expf(2.0f * s2);
    float rho = 0.99f * ((ex - 1.0f) * __builtin_amdgcn_rcpf(ex + 1.0f));
    float sxx = sx * sx, syy = sy * sy;
    float sxy = rho * sx * sy;
    float det = sxx * syy - sxy * sxy;               // >= 0.0199
    float inv_det = 1.0f / det;

    float a = -0.5f * syy * inv_det;
    float b =  sxy * inv_det;
    float c = -0.5f * sxx * inv_det;

    int i = tok % NTOK;
    float pack;
    if (i == 0) { a = 0.0f; b = 0.0f; c = 0.0f; pack = 0.0f; }
    else {
        int ip = i - 1;
        int ri = ip / 24;
        int ci = ip - ri * 24;
        pack = (float)(ri * 32 + ci);
    }
    if (sub == 0)
        coef[tok] = make_float4(a, b, c, pack);      // dup groups rewrite same value
}

// ---------------------------------------------------------------------------
// Kernel B v4: elementwise mask, 8 elems/thread (2x float4 nt streams).
// rowmax(kernel)==1 structurally, so probs = clip(exp(w), eps, 1-eps).
// v4: sigmoid chain fused algebraically:
//   sigmoid(10*(log num - log den)) == 1 / (1 + (den/num)^10)
// (exact identity; replaces 2 logs + 1 exp with 1 rcp + 4 muls; overflow of
// (den/num)^10 -> inf -> rcp -> 0 matches exp-path saturation, underflow -> 1
// likewise). w computation (the absmax-dominating term) is untouched.
// 8 < 577 so still at most one row crossing per thread; last thread has
// j0 = 569 -> no crossing, so coef[row0+1] access stays in-bounds.
// ---------------------------------------------------------------------------
__global__ __launch_bounds__(256) void mask_kernel(
    const f32x4* __restrict__ u4, const float4* __restrict__ coef,
    f32x4* __restrict__ out4)
{
    int vid = blockIdx.x * 256 + threadIdx.x;
    if (vid >= TOTAL_V8) return;

    int e0 = vid * 8;
    unsigned row0 = (unsigned)e0 / 577u;             // magic-div
    int j0 = e0 - (int)row0 * 577;

    unsigned row1 = row0 + ((j0 + 7 >= 577) ? 1u : 0u);
    float4 cf0 = coef[row0];
    float4 cf1 = coef[row1];
    f32x4 uu0 = __builtin_nontemporal_load(&u4[2 * vid]);
    f32x4 uu1 = __builtin_nontemporal_load(&u4[2 * vid + 1]);

    float um[8] = {uu0[0], uu0[1], uu0[2], uu0[3],
                   uu1[0], uu1[1], uu1[2], uu1[3]};
    float res[8];

    #pragma unroll
    for (int m = 0; m < 8; ++m) {
        int j = j0 + m;
        bool crossed = (j >= 577);
        if (crossed) j -= 577;
        float ca = crossed ? cf1.x : cf0.x;
        float cb = crossed ? cf1.y : cf0.y;
        float cc = crossed ? cf1.z : cf0.z;
        int   rc = (int)(crossed ? cf1.w : cf0.w);

        float dx = 0.0f, dy = 0.0f;
        if (j > 0) {
            unsigned jj = (unsigned)(j - 1);
            unsigned rj = jj / 24u;                  // magic-div
            unsigned cj = jj - rj * 24u;
            dx = (float)((rc >> 5) - (int)rj);
            dy = (float)((rc & 31) - (int)cj);
        }

        // w = a*dx^2 + b*dx*dy + c*dy^2  (<= 0)
        float w = fmaf(fmaf(ca, dx, cb * dy), dx, cc * (dy * dy));

        float p = __expf(w);
        p = fminf(fmaxf(p, EPS_F), 1.0f - EPS_F);

        float uk  = um[m];
        float num = p * uk;                          // >= 1e-12
        float den = (1.0f - p) * (1.0f - uk);

        float r   = den * __builtin_amdgcn_rcpf(num);
        float r2  = r * r;
        float r4  = r2 * r2;
        float r8  = r4 * r4;
        float r10 = r8 * r2;                         // (den/num)^10
        res[m] = __builtin_amdgcn_rcpf(1.0f + r10);
    }

    f32x4 o0, o1;
    o0[0] = res[0]; o0[1] = res[1]; o0[2] = res[2]; o0[3] = res[3];
    o1[0] = res[4]; o1[1] = res[5]; o1[2] = res[6]; o1[3] = res[7];
    __builtin_nontemporal_store(o0, &out4[2 * vid]);
    __builtin_nontemporal_store(o1, &out4[2 * vid + 1]);
}

// ---------------------------------------------------------------------------
extern "C" void kernel_launch(void* const* d_in, const int* in_sizes, int n_in,
                              void* d_out, int out_size, void* d_ws, size_t ws_size,
                              hipStream_t stream) {
    const float* q  = (const float*)d_in[0];
    const float* W1 = (const float*)d_in[1];
    const float* b1 = (const float*)d_in[2];
    const float* W2 = (const float*)d_in[3];
    const float* b2 = (const float*)d_in[4];
    const float* u  = (const float*)d_in[5];
    // d_in[6] = dists: recomputed on the fly, not loaded.

    float4* coef = (float4*)d_ws;                    // 886 KB scratch

    sigma_coef_kernel<<<(BHN * 4 + 255) / 256, 256, 0, stream>>>(q, W1, b1, W2, b2, coef);
    mask_kernel<<<(TOTAL_V8 + 255) / 256, 256, 0, stream>>>(
        (const f32x4*)u, coef, (f32x4*)d_out);
}